// Round 4
// baseline (500.904 us; speedup 1.0000x reference)
//
#include <hip/hip_runtime.h>
#include <hip/hip_bf16.h>

// SupernodePooling pipeline:
//   prep:   Wt/Wb = bf16(W1_top/bot)^T, Wint = Win^T
//   xcomp:  x = feat@W_in + b_in + sincos(pos) -> bf16, chunk-XOR-swizzled [N,192]
//   agemm<true>:  b = x[sup] @ W1_bot + b1 -> bf16 rows interleaved in C (stride 384)
//   agemm<false>: a = x @ W1_top -> bf16 [N,192] plain, IN PLACE over x buffer
//   pool:   g[s] = mean_{32 edges} gelu(a[src]+b[s]) -> f32 in place over C
//   gemm192: out = g @ W2 + b2
// Identities: concat-GEMM splits; segment-mean commutes with W2; seg[e]=e/32.

#define HD 192
#define INF 16
#define N_NODES 262144
#define N_SUP 16384
#define ROWB 384      // bytes per 192-bf16 row

typedef __attribute__((ext_vector_type(8))) short bf16x8;
typedef __attribute__((ext_vector_type(4))) float f32x4;

__device__ __forceinline__ unsigned f2bf(float f) {
    unsigned x = __float_as_uint(f);
    return (x + 0x7fffu + ((x >> 16) & 1u)) >> 16;   // RNE
}
__device__ __forceinline__ float bf2f(unsigned short u) {
    return __uint_as_float(((unsigned)u) << 16);
}
__device__ __forceinline__ void gload16(const void* g, void* l) {
    __builtin_amdgcn_global_load_lds(
        (const __attribute__((address_space(1))) unsigned int*)g,
        (__attribute__((address_space(3))) unsigned int*)l, 16, 0, 0);
}
// tanh-form GELU: max dev from exact erf-GELU ~5e-4
__device__ __forceinline__ float gelu_t(float v) {
    const float v2 = v * v;
    const float m  = v * fmaf(v2, -0.1029392f, -2.3021178f);  // -2*log2(e)*0.79788456*(1+0.044715 v^2)
    return v * __fdividef(1.f, 1.f + exp2f(m));
}

// ---------------------------------------------------------------------------
__global__ void prep_kernel(const float* __restrict__ W1,
                            const float* __restrict__ Win,
                            unsigned short* __restrict__ Wt,
                            unsigned short* __restrict__ Wb,
                            float* __restrict__ Wint)
{
    const int i = blockIdx.x * 256 + threadIdx.x;
    if (i < 36864) {
        const int n = i / HD, k = i % HD;
        Wt[i] = (unsigned short)f2bf(W1[k * HD + n]);
    } else if (i < 73728) {
        const int j = i - 36864;
        const int n = j / HD, k = j % HD;
        Wb[j] = (unsigned short)f2bf(W1[(size_t)(HD + k) * HD + n]);
    } else if (i < 76800) {
        const int j = i - 73728;
        const int c = j / INF, k = j % INF;
        Wint[j] = Win[k * HD + c];
    }
}

// ---------------------------------------------------------------------------
// xcomp: x[n][c] = dot(feat[n], Win[:,c]) + bin[c] + sin/cos(pos[n][c/64]*om)
// Output bf16, chunk-swizzled: chunk c of row r stored at position c^(r&7).
// 64 rows/block, wave-local (no barriers). Lane l owns cols {l, l+64, l+128}.
// ---------------------------------------------------------------------------
__global__ __launch_bounds__(256, 4)
void xcomp_kernel(const float* __restrict__ feat,
                  const float* __restrict__ pos,
                  const float* __restrict__ Wint,   // [192 c][16 k]
                  const float* __restrict__ bin,
                  unsigned short* __restrict__ xswz)
{
    __shared__ __align__(16) float feat_s[4][256];             // 16 rows x 16 per wave
    __shared__ float pos_s[4][48];
    __shared__ __align__(16) unsigned short dstg[4][16 * HD];  // 16 rows per wave

    const int t = threadIdx.x, w = t >> 6, l = t & 63;
    const int row0 = blockIdx.x * 64 + w * 16;

    float win[3][INF];
    #pragma unroll
    for (int d = 0; d < 3; ++d)
        #pragma unroll
        for (int q = 0; q < 4; ++q)
            *reinterpret_cast<float4*>(&win[d][q * 4]) =
                *reinterpret_cast<const float4*>(Wint + (size_t)(l + 64 * d) * INF + q * 4);
    float bcol[3];
    #pragma unroll
    for (int d = 0; d < 3; ++d) bcol[d] = bin[l + 64 * d];
    const float om = exp2f(-(float)(l & 31) * 0.41524101186098287f);
    const float phase = (l < 32) ? 0.f : 1.57079632679f;   // cos = sin(+pi/2)

    // stage 16 rows of feat/pos (wave-local)
    {
        const float4 f4 = *reinterpret_cast<const float4*>(
            feat + (size_t)(row0 + (l >> 2)) * INF + (l & 3) * 4);
        *reinterpret_cast<float4*>(&feat_s[w][(l >> 2) * 16 + (l & 3) * 4]) = f4;
        if (l < 48) pos_s[w][l] = pos[(size_t)row0 * 3 + l];
    }

    for (int r = 0; r < 16; ++r) {
        float fr[INF];
        #pragma unroll
        for (int q = 0; q < 4; ++q)
            *reinterpret_cast<float4*>(&fr[q * 4]) =
                *reinterpret_cast<const float4*>(&feat_s[w][r * 16 + q * 4]);
        #pragma unroll
        for (int d = 0; d < 3; ++d) {
            const float pe = __sinf(fmaf(pos_s[w][r * 3 + d], om, phase));
            float acc = bcol[d] + pe;
            #pragma unroll
            for (int k = 0; k < INF; ++k) acc = fmaf(fr[k], win[d][k], acc);
            dstg[w][r * HD + l + 64 * d] = (unsigned short)f2bf(acc);
        }
    }

    // readback + swizzled coalesced store (wave-local)
    #pragma unroll
    for (int q = 0; q < 6; ++q) {
        const int id = q * 64 + l;          // 0..383
        const int rl = id / 24, c = id % 24;
        const bf16x8 v = *reinterpret_cast<const bf16x8*>(&dstg[w][rl * HD + c * 8]);
        *reinterpret_cast<bf16x8*>((char*)xswz +
            (size_t)(row0 + rl) * ROWB + ((c ^ (rl & 7)) * 16)) = v;
    }
}

// ---------------------------------------------------------------------------
// agemm: out = bf16( X @ Wt^T (+bias) ), X = swizzled bf16 [.,192], K=192.
// 4 waves: wave w -> cols [w*48,w*48+48). global_load_lds staging, 2-buf LDS,
// dstg aliases consumed buffer. A-frag reads XOR-swizzled -> bank-balanced.
// ---------------------------------------------------------------------------
template<bool GATHER>
__global__ __launch_bounds__(256, 3)
void agemm_kernel(const unsigned short* __restrict__ xswz,
                  const int* __restrict__ gidx,
                  const unsigned short* __restrict__ Wt,   // [192 n][192 k]
                  const float* __restrict__ bias,
                  unsigned short* __restrict__ outp,
                  const int out_stride,                    // elems
                  const int ntiles)
{
    __shared__ __align__(16) unsigned short xbuf[2][64 * HD];  // 2 x 24576 B
    __shared__ int nid[64];

    const int t = threadIdx.x, w = t >> 6, l = t & 63;

    bf16x8 bfr[3][6];
    #pragma unroll
    for (int ct = 0; ct < 3; ++ct) {
        const int col = w * 48 + ct * 16 + (l & 15);
        const unsigned short* wp = Wt + (size_t)col * HD + (l >> 4) * 8;
        #pragma unroll
        for (int ks = 0; ks < 6; ++ks)
            bfr[ct][ks] = *reinterpret_cast<const bf16x8*>(wp + ks * 32);
    }
    float bias_c[3] = {0.f, 0.f, 0.f};
    if (GATHER) {
        #pragma unroll
        for (int ct = 0; ct < 3; ++ct) bias_c[ct] = bias[w * 48 + ct * 16 + (l & 15)];
        if (t < 64) nid[t] = gidx[blockIdx.x * 64 + t];
        __syncthreads();
    }

    auto STAGE = [&](int tile, int buf) {
        char* lbase = (char*)&xbuf[buf][0];
        if constexpr (GATHER) {
            #pragma unroll
            for (int i = 0; i < 6; ++i) {
                const int slot = w * 64 + i * 256 + l;
                const int r = slot / 24, p = slot % 24;
                const int node = nid[r];
                const char* src = (const char*)xswz + (size_t)node * ROWB +
                                  (((p ^ (r & 7)) ^ (node & 7)) * 16);
                gload16(src, lbase + w * 1024 + i * 4096);
            }
        } else {
            const char* gb = (const char*)xswz +
                             (size_t)(blockIdx.x * ntiles + tile) * 64 * ROWB;
            #pragma unroll
            for (int i = 0; i < 6; ++i)
                gload16(gb + w * 1024 + i * 4096 + l * 16, lbase + w * 1024 + i * 4096);
        }
    };

    STAGE(0, 0);
    __syncthreads();

    for (int tt = 0; tt < ntiles; ++tt) {
        const int cur = tt & 1;
        if (tt + 1 < ntiles) STAGE(tt + 1, cur ^ 1);

        f32x4 acc[4][3];
        #pragma unroll
        for (int rt = 0; rt < 4; ++rt)
            #pragma unroll
            for (int ct = 0; ct < 3; ++ct)
                acc[rt][ct] = (f32x4){0.f, 0.f, 0.f, 0.f};

        const char* xb = (const char*)&xbuf[cur][0];
        #pragma unroll
        for (int ks = 0; ks < 6; ++ks) {
            bf16x8 af[4];
            #pragma unroll
            for (int rt = 0; rt < 4; ++rt) {
                const int row = rt * 16 + (l & 15);
                const int p = (ks * 4 + (l >> 4)) ^ (l & 7);   // row&7 == l&7
                af[rt] = *reinterpret_cast<const bf16x8*>(xb + row * ROWB + p * 16);
            }
            #pragma unroll
            for (int rt = 0; rt < 4; ++rt)
                #pragma unroll
                for (int ct = 0; ct < 3; ++ct)
                    acc[rt][ct] = __builtin_amdgcn_mfma_f32_16x16x32_bf16(
                        af[rt], bfr[ct][ks], acc[rt][ct], 0, 0, 0);
        }
        __syncthreads();   // vmcnt(0): next tile staged; all reads of cur done

        // D (+bias) -> dstg (= xbuf[cur]), XOR-swizzled; wave-local column band
        char* db = (char*)&xbuf[cur][0];
        #pragma unroll
        for (int rt = 0; rt < 4; ++rt)
            #pragma unroll
            for (int ct = 0; ct < 3; ++ct) {
                const int col = w * 48 + ct * 16 + (l & 15);
                const int ch = col >> 3, off = col & 7;
                #pragma unroll
                for (int j = 0; j < 4; ++j) {
                    const int row = rt * 16 + (l >> 4) * 4 + j;
                    *reinterpret_cast<unsigned short*>(
                        db + row * ROWB + ((ch ^ (row & 7)) * 16) + off * 2) =
                        (unsigned short)f2bf(acc[rt][ct][j] + bias_c[ct]);
                }
            }
        // readback + plain store (wave-local band: chunks [w*6, w*6+6))
        const size_t orow0 = GATHER ? (size_t)blockIdx.x * 64
                                    : (size_t)(blockIdx.x * ntiles + tt) * 64;
        #pragma unroll
        for (int q = 0; q < 6; ++q) {
            const int id = q * 64 + l;      // 0..383
            const int rid = id / 6, cc = id % 6;
            const int c = w * 6 + cc;
            const bf16x8 v = *reinterpret_cast<const bf16x8*>(
                db + rid * ROWB + ((c ^ (rid & 7)) * 16));
            *reinterpret_cast<bf16x8*>(outp + (orow0 + rid) * out_stride + c * 8) = v;
        }
        __syncthreads();   // dstg reads done before next STAGE overwrites
    }
}

// ---------------------------------------------------------------------------
// pool: g[s] = (1/32) * sum_e gelu(a[src]+b[s]); b bf16 rows at stride 384
// elems in C, g f32 overwrites same rows. 4 supernodes x 48 thr.
// ---------------------------------------------------------------------------
__global__ __launch_bounds__(192)
void pool_kernel(const unsigned short* __restrict__ a,   // [N,192] bf16 plain
                 const unsigned short* __restrict__ bC,
                 const int* __restrict__ src_idx,
                 float* __restrict__ g)
{
    __shared__ int sA[128];
    const int t = threadIdx.x;
    if (t < 128) sA[t] = src_idx[(size_t)blockIdx.x * 128 + t];
    __syncthreads();

    const int sl = t / 48;
    const int c4 = t % 48;
    const size_t s = (size_t)blockIdx.x * 4 + sl;
    const int* sp = sA + sl * 32;

    const ushort4 bu = *reinterpret_cast<const ushort4*>(bC + s * 384 + c4 * 4);
    const float b0 = bf2f(bu.x), b1v = bf2f(bu.y), b2v = bf2f(bu.z), b3v = bf2f(bu.w);

    float a0 = 0.f, a1 = 0.f, a2 = 0.f, a3 = 0.f;
    #pragma unroll 8
    for (int e = 0; e < 32; ++e) {
        const int src = sp[e];
        const ushort4 u = *reinterpret_cast<const ushort4*>(a + (size_t)src * HD + c4 * 4);
        a0 += gelu_t(bf2f(u.x) + b0);
        a1 += gelu_t(bf2f(u.y) + b1v);
        a2 += gelu_t(bf2f(u.z) + b2v);
        a3 += gelu_t(bf2f(u.w) + b3v);
    }
    __syncthreads();   // all b reads done before aliased g writes
    float4 r;
    r.x = a0 * 0.03125f; r.y = a1 * 0.03125f; r.z = a2 * 0.03125f; r.w = a3 * 0.03125f;
    *reinterpret_cast<float4*>(g + s * HD + c4 * 4) = r;
}

// ---------------------------------------------------------------------------
// out = A[rows,192] @ W[192,192] + bias   (f32)
// ---------------------------------------------------------------------------
__global__ __launch_bounds__(256, 2)
void gemm192_kernel(const float* __restrict__ A,
                    const float* __restrict__ W,
                    const float* __restrict__ bias,
                    float* __restrict__ out)
{
    __shared__ float xsf[64][196];
    __shared__ float wchunk[32][HD];
    const int t    = threadIdx.x;
    const int row0 = blockIdx.x * 64;

    const float4* ap = reinterpret_cast<const float4*>(A + (size_t)row0 * HD);
    #pragma unroll
    for (int q = 0; q < 12; ++q) {
        const int f4 = t + q * 256;
        const int r = f4 / 48, c = f4 % 48;
        *reinterpret_cast<float4*>(&xsf[r][c * 4]) = ap[f4];
    }

    const int tr = t >> 4;
    const int tc = t & 15;
    float acc[4][12];
    #pragma unroll
    for (int i = 0; i < 4; ++i)
        #pragma unroll
        for (int j = 0; j < 12; ++j) acc[i][j] = 0.f;

    for (int kc = 0; kc < 6; ++kc) {
        __syncthreads();
        {
            const float4* wp = reinterpret_cast<const float4*>(W + kc * 32 * HD);
            float4* wsp = reinterpret_cast<float4*>(&wchunk[0][0]);
            #pragma unroll
            for (int q = 0; q < 6; ++q) wsp[t + q * 256] = wp[t + q * 256];
        }
        __syncthreads();
        #pragma unroll 4
        for (int k = 0; k < 32; ++k) {
            const int kg = kc * 32 + k;
            float xv[4];
            #pragma unroll
            for (int i = 0; i < 4; ++i) xv[i] = xsf[tr * 4 + i][kg];
            float wv[12];
            #pragma unroll
            for (int j4 = 0; j4 < 3; ++j4)
                *reinterpret_cast<float4*>(&wv[j4 * 4]) =
                    *reinterpret_cast<const float4*>(&wchunk[k][tc * 12 + j4 * 4]);
            #pragma unroll
            for (int i = 0; i < 4; ++i)
                #pragma unroll
                for (int j = 0; j < 12; ++j)
                    acc[i][j] = fmaf(xv[i], wv[j], acc[i][j]);
        }
    }

    float bb[12];
    #pragma unroll
    for (int j = 0; j < 12; ++j) bb[j] = bias[tc * 12 + j];

    #pragma unroll
    for (int i = 0; i < 4; ++i) {
        float* o = out + (size_t)(row0 + tr * 4 + i) * HD + tc * 12;
        #pragma unroll
        for (int j4 = 0; j4 < 3; ++j4) {
            float4 v;
            v.x = acc[i][j4 * 4 + 0] + bb[j4 * 4 + 0];
            v.y = acc[i][j4 * 4 + 1] + bb[j4 * 4 + 1];
            v.z = acc[i][j4 * 4 + 2] + bb[j4 * 4 + 2];
            v.w = acc[i][j4 * 4 + 3] + bb[j4 * 4 + 3];
            *reinterpret_cast<float4*>(o + j4 * 4) = v;
        }
    }
}

extern "C" void kernel_launch(void* const* d_in, const int* in_sizes, int n_in,
                              void* d_out, int out_size, void* d_ws, size_t ws_size,
                              hipStream_t stream)
{
    const float* feat = (const float*)d_in[0];
    const float* pos  = (const float*)d_in[1];
    const int*   sup  = (const int*)d_in[2];
    const int*   src  = (const int*)d_in[4];
    const float* Win  = (const float*)d_in[6];
    const float* bin  = (const float*)d_in[7];
    const float* W1   = (const float*)d_in[8];   // [384,192]
    const float* b1   = (const float*)d_in[9];
    const float* W2   = (const float*)d_in[10];  // [192,192]
    const float* b2   = (const float*)d_in[11];

    char* ws = (char*)d_ws;
    unsigned short* Wt   = (unsigned short*)ws;              //  73728 B
    unsigned short* Wb   = (unsigned short*)(ws + 73728);    //  73728 B
    float*          Wint = (float*)(ws + 147456);            //  12288 B
    unsigned short* x    = (unsigned short*)(ws + 159744);   // 100663296 B (x, then a in-place)
    char*           C    = ws + 159744 + 100663296;          //  12582912 B
    float* out = (float*)d_out;

    prep_kernel<<<300, 256, 0, stream>>>(W1, Win, Wt, Wb, Wint);
    // x (bf16, chunk-swizzled)
    xcomp_kernel<<<N_NODES / 64, 256, 0, stream>>>(feat, pos, Wint, bin, x);
    // b = x[sup] @ W1_bot + b1 -> bf16 rows in C (stride 384 elems)
    agemm_kernel<true><<<N_SUP / 64, 256, 0, stream>>>(
        x, sup, Wb, b1, (unsigned short*)C, 384, 1);
    // a = x @ W1_top -> plain bf16, in place over x
    agemm_kernel<false><<<N_NODES / 256, 256, 0, stream>>>(
        x, nullptr, Wt, nullptr, x, HD, 4);
    // g = segment-mean(gelu(a[src] + b[dst])) -> f32 in place over C
    pool_kernel<<<N_SUP / 4, 192, 0, stream>>>(x, (const unsigned short*)C, src, (float*)C);
    // out = g @ W2 + b2
    gemm192_kernel<<<N_SUP / 64, 256, 0, stream>>>((const float*)C, W2, b2, out);
}

// Round 5
// 261.398 us; speedup vs baseline: 1.9163x; 1.9163x over previous
//
#include <hip/hip_runtime.h>
#include <hip/hip_bf16.h>

// SupernodePooling pipeline:
//   prep:   Wt/Wb = bf16(W1_top/bot)^T, Wint = Win^T
//   xcomp:  x = feat@W_in + b_in + sincos(pos) -> bf16, chunk-XOR-swizzled [N,192]
//   agemm<true>:  b = x[sup] @ W1_bot + b1 -> bf16 rows interleaved in C (stride 384)
//   agemm<false>: a = x @ W1_top -> bf16 [N,192] plain, IN PLACE over x buffer
//   pool:   g[s] = mean_{32 edges} gelu(a[src]+b[s]) -> f32 in place over C
//   gemm192: out = g @ W2 + b2
// Identities: concat-GEMM splits; segment-mean commutes with W2; seg[e]=e/32.
// NOTE: launch_bounds are (256,2) everywhere register-heavy — (256,3)/(256,4)
// capped VGPRs at 85/64 and spilled win[]/bfr[]/acc[] to scratch (round-4
// post-mortem: 466 MB FETCH / 418 MB WRITE of pure spill traffic in xcomp).

#define HD 192
#define INF 16
#define N_NODES 262144
#define N_SUP 16384
#define ROWB 384      // bytes per 192-bf16 row

typedef __attribute__((ext_vector_type(8))) short bf16x8;
typedef __attribute__((ext_vector_type(4))) float f32x4;

__device__ __forceinline__ unsigned f2bf(float f) {
    unsigned x = __float_as_uint(f);
    return (x + 0x7fffu + ((x >> 16) & 1u)) >> 16;   // RNE
}
__device__ __forceinline__ float bf2f(unsigned short u) {
    return __uint_as_float(((unsigned)u) << 16);
}
__device__ __forceinline__ void gload16(const void* g, void* l) {
    __builtin_amdgcn_global_load_lds(
        (const __attribute__((address_space(1))) unsigned int*)g,
        (__attribute__((address_space(3))) unsigned int*)l, 16, 0, 0);
}
// tanh-form GELU: max dev from exact erf-GELU ~5e-4 (passed r4 at absmax 0.0156)
__device__ __forceinline__ float gelu_t(float v) {
    const float v2 = v * v;
    const float m  = v * fmaf(v2, -0.1029392f, -2.3021178f);
    return v * __fdividef(1.f, 1.f + exp2f(m));
}

// ---------------------------------------------------------------------------
__global__ void prep_kernel(const float* __restrict__ W1,
                            const float* __restrict__ Win,
                            unsigned short* __restrict__ Wt,
                            unsigned short* __restrict__ Wb,
                            float* __restrict__ Wint)
{
    const int i = blockIdx.x * 256 + threadIdx.x;
    if (i < 36864) {
        const int n = i / HD, k = i % HD;
        Wt[i] = (unsigned short)f2bf(W1[k * HD + n]);
    } else if (i < 73728) {
        const int j = i - 36864;
        const int n = j / HD, k = j % HD;
        Wb[j] = (unsigned short)f2bf(W1[(size_t)(HD + k) * HD + n]);
    } else if (i < 76800) {
        const int j = i - 73728;
        const int c = j / INF, k = j % INF;
        Wint[j] = Win[k * HD + c];
    }
}

// ---------------------------------------------------------------------------
// xcomp: x[n][c] = dot(feat[n], Win[:,c]) + bin[c] + sin/cos(pos[n][c/64]*om)
// Output bf16, chunk-swizzled: 16B chunk c of row r stored at chunk c^(r&7).
// 64 rows/block, wave-local (no barriers). Lane l owns cols {l, l+64, l+128}.
// ---------------------------------------------------------------------------
__global__ __launch_bounds__(256, 2)
void xcomp_kernel(const float* __restrict__ feat,
                  const float* __restrict__ pos,
                  const float* __restrict__ Wint,   // [192 c][16 k]
                  const float* __restrict__ bin,
                  unsigned short* __restrict__ xswz)
{
    __shared__ __align__(16) float feat_s[4][256];             // 16 rows x 16 per wave
    __shared__ float pos_s[4][48];
    __shared__ __align__(16) unsigned short dstg[4][16 * HD];  // 16 rows per wave

    const int t = threadIdx.x, w = t >> 6, l = t & 63;
    const int row0 = blockIdx.x * 64 + w * 16;

    float win[3][INF];
    #pragma unroll
    for (int d = 0; d < 3; ++d)
        #pragma unroll
        for (int q = 0; q < 4; ++q)
            *reinterpret_cast<float4*>(&win[d][q * 4]) =
                *reinterpret_cast<const float4*>(Wint + (size_t)(l + 64 * d) * INF + q * 4);
    float bcol[3];
    #pragma unroll
    for (int d = 0; d < 3; ++d) bcol[d] = bin[l + 64 * d];
    const float om = exp2f(-(float)(l & 31) * 0.41524101186098287f);
    const float phase = (l < 32) ? 0.f : 1.57079632679f;   // cos = sin(+pi/2)

    // stage 16 rows of feat/pos (wave-local)
    {
        const float4 f4 = *reinterpret_cast<const float4*>(
            feat + (size_t)(row0 + (l >> 2)) * INF + (l & 3) * 4);
        *reinterpret_cast<float4*>(&feat_s[w][(l >> 2) * 16 + (l & 3) * 4]) = f4;
        if (l < 48) pos_s[w][l] = pos[(size_t)row0 * 3 + l];
    }

    for (int r = 0; r < 16; ++r) {
        float fr[INF];
        #pragma unroll
        for (int q = 0; q < 4; ++q)
            *reinterpret_cast<float4*>(&fr[q * 4]) =
                *reinterpret_cast<const float4*>(&feat_s[w][r * 16 + q * 4]);
        #pragma unroll
        for (int d = 0; d < 3; ++d) {
            const float pe = __sinf(fmaf(pos_s[w][r * 3 + d], om, phase));
            float acc = bcol[d] + pe;
            #pragma unroll
            for (int k = 0; k < INF; ++k) acc = fmaf(fr[k], win[d][k], acc);
            dstg[w][r * HD + l + 64 * d] = (unsigned short)f2bf(acc);
        }
    }

    // readback + swizzled coalesced store (wave-local)
    #pragma unroll
    for (int q = 0; q < 6; ++q) {
        const int id = q * 64 + l;          // 0..383
        const int rl = id / 24, c = id % 24;
        const bf16x8 v = *reinterpret_cast<const bf16x8*>(&dstg[w][rl * HD + c * 8]);
        *reinterpret_cast<bf16x8*>((char*)xswz +
            (size_t)(row0 + rl) * ROWB + ((c ^ (rl & 7)) * 16)) = v;
    }
}

// ---------------------------------------------------------------------------
// agemm: out = bf16( X @ Wt^T (+bias) ), X = swizzled bf16 [.,192], K=192.
// 4 waves: wave w -> cols [w*48,w*48+48). global_load_lds staging, 2-buf LDS,
// dstg aliases consumed buffer. A-frag reads XOR-swizzled -> bank-balanced.
// ---------------------------------------------------------------------------
template<bool GATHER>
__global__ __launch_bounds__(256, 2)
void agemm_kernel(const unsigned short* __restrict__ xswz,
                  const int* __restrict__ gidx,
                  const unsigned short* __restrict__ Wt,   // [192 n][192 k]
                  const float* __restrict__ bias,
                  unsigned short* __restrict__ outp,
                  const int out_stride,                    // elems
                  const int ntiles)
{
    __shared__ __align__(16) unsigned short xbuf[2][64 * HD];  // 2 x 24576 B
    __shared__ int nid[64];

    const int t = threadIdx.x, w = t >> 6, l = t & 63;

    bf16x8 bfr[3][6];
    #pragma unroll
    for (int ct = 0; ct < 3; ++ct) {
        const int col = w * 48 + ct * 16 + (l & 15);
        const unsigned short* wp = Wt + (size_t)col * HD + (l >> 4) * 8;
        #pragma unroll
        for (int ks = 0; ks < 6; ++ks)
            bfr[ct][ks] = *reinterpret_cast<const bf16x8*>(wp + ks * 32);
    }
    float bias_c[3] = {0.f, 0.f, 0.f};
    if (GATHER) {
        #pragma unroll
        for (int ct = 0; ct < 3; ++ct) bias_c[ct] = bias[w * 48 + ct * 16 + (l & 15)];
        if (t < 64) nid[t] = gidx[blockIdx.x * 64 + t];
        __syncthreads();
    }

    auto STAGE = [&](int tile, int buf) {
        char* lbase = (char*)&xbuf[buf][0];
        if constexpr (GATHER) {
            #pragma unroll
            for (int i = 0; i < 6; ++i) {
                const int slot = w * 64 + i * 256 + l;
                const int r = slot / 24, p = slot % 24;
                const int node = nid[r];
                const char* src = (const char*)xswz + (size_t)node * ROWB +
                                  (((p ^ (r & 7)) ^ (node & 7)) * 16);
                gload16(src, lbase + w * 1024 + i * 4096);
            }
        } else {
            const char* gb = (const char*)xswz +
                             (size_t)(blockIdx.x * ntiles + tile) * 64 * ROWB;
            #pragma unroll
            for (int i = 0; i < 6; ++i)
                gload16(gb + w * 1024 + i * 4096 + l * 16, lbase + w * 1024 + i * 4096);
        }
    };

    STAGE(0, 0);
    __syncthreads();

    for (int tt = 0; tt < ntiles; ++tt) {
        const int cur = tt & 1;
        if (tt + 1 < ntiles) STAGE(tt + 1, cur ^ 1);

        f32x4 acc[4][3];
        #pragma unroll
        for (int rt = 0; rt < 4; ++rt)
            #pragma unroll
            for (int ct = 0; ct < 3; ++ct)
                acc[rt][ct] = (f32x4){0.f, 0.f, 0.f, 0.f};

        const char* xb = (const char*)&xbuf[cur][0];
        #pragma unroll
        for (int ks = 0; ks < 6; ++ks) {
            bf16x8 af[4];
            #pragma unroll
            for (int rt = 0; rt < 4; ++rt) {
                const int row = rt * 16 + (l & 15);
                const int p = (ks * 4 + (l >> 4)) ^ (l & 7);   // row&7 == l&7
                af[rt] = *reinterpret_cast<const bf16x8*>(xb + row * ROWB + p * 16);
            }
            #pragma unroll
            for (int rt = 0; rt < 4; ++rt)
                #pragma unroll
                for (int ct = 0; ct < 3; ++ct)
                    acc[rt][ct] = __builtin_amdgcn_mfma_f32_16x16x32_bf16(
                        af[rt], bfr[ct][ks], acc[rt][ct], 0, 0, 0);
        }
        __syncthreads();   // vmcnt(0): next tile staged; all reads of cur done

        // D (+bias) -> dstg (= xbuf[cur]), XOR-swizzled; wave-local column band
        char* db = (char*)&xbuf[cur][0];
        #pragma unroll
        for (int rt = 0; rt < 4; ++rt)
            #pragma unroll
            for (int ct = 0; ct < 3; ++ct) {
                const int col = w * 48 + ct * 16 + (l & 15);
                const int ch = col >> 3, off = col & 7;
                #pragma unroll
                for (int j = 0; j < 4; ++j) {
                    const int row = rt * 16 + (l >> 4) * 4 + j;
                    *reinterpret_cast<unsigned short*>(
                        db + row * ROWB + ((ch ^ (row & 7)) * 16) + off * 2) =
                        (unsigned short)f2bf(acc[rt][ct][j] + bias_c[ct]);
                }
            }
        // readback + plain store (wave-local band: chunks [w*6, w*6+6))
        const size_t orow0 = GATHER ? (size_t)blockIdx.x * 64
                                    : (size_t)(blockIdx.x * ntiles + tt) * 64;
        #pragma unroll
        for (int q = 0; q < 6; ++q) {
            const int id = q * 64 + l;      // 0..383
            const int rid = id / 6, cc = id % 6;
            const int c = w * 6 + cc;
            const bf16x8 v = *reinterpret_cast<const bf16x8*>(
                db + rid * ROWB + ((c ^ (rid & 7)) * 16));
            *reinterpret_cast<bf16x8*>(outp + (orow0 + rid) * out_stride + c * 8) = v;
        }
        __syncthreads();   // dstg reads done before next STAGE overwrites
    }
}

// ---------------------------------------------------------------------------
// pool: g[s] = (1/32) * sum_e gelu(a[src]+b[s]); b bf16 rows at stride 384
// elems in C, g f32 overwrites same rows. 4 supernodes x 48 thr.
// ---------------------------------------------------------------------------
__global__ __launch_bounds__(192)
void pool_kernel(const unsigned short* __restrict__ a,   // [N,192] bf16 plain
                 const unsigned short* __restrict__ bC,
                 const int* __restrict__ src_idx,
                 float* __restrict__ g)
{
    __shared__ int sA[128];
    const int t = threadIdx.x;
    if (t < 128) sA[t] = src_idx[(size_t)blockIdx.x * 128 + t];
    __syncthreads();

    const int sl = t / 48;
    const int c4 = t % 48;
    const size_t s = (size_t)blockIdx.x * 4 + sl;
    const int* sp = sA + sl * 32;

    const ushort4 bu = *reinterpret_cast<const ushort4*>(bC + s * 384 + c4 * 4);
    const float b0 = bf2f(bu.x), b1v = bf2f(bu.y), b2v = bf2f(bu.z), b3v = bf2f(bu.w);

    float a0 = 0.f, a1 = 0.f, a2 = 0.f, a3 = 0.f;
    #pragma unroll 8
    for (int e = 0; e < 32; ++e) {
        const int src = sp[e];
        const ushort4 u = *reinterpret_cast<const ushort4*>(a + (size_t)src * HD + c4 * 4);
        a0 += gelu_t(bf2f(u.x) + b0);
        a1 += gelu_t(bf2f(u.y) + b1v);
        a2 += gelu_t(bf2f(u.z) + b2v);
        a3 += gelu_t(bf2f(u.w) + b3v);
    }
    __syncthreads();   // all b reads done before aliased g writes
    float4 r;
    r.x = a0 * 0.03125f; r.y = a1 * 0.03125f; r.z = a2 * 0.03125f; r.w = a3 * 0.03125f;
    *reinterpret_cast<float4*>(g + s * HD + c4 * 4) = r;
}

// ---------------------------------------------------------------------------
// out = A[rows,192] @ W[192,192] + bias   (f32)
// ---------------------------------------------------------------------------
__global__ __launch_bounds__(256, 2)
void gemm192_kernel(const float* __restrict__ A,
                    const float* __restrict__ W,
                    const float* __restrict__ bias,
                    float* __restrict__ out)
{
    __shared__ float xsf[64][196];
    __shared__ float wchunk[32][HD];
    const int t    = threadIdx.x;
    const int row0 = blockIdx.x * 64;

    const float4* ap = reinterpret_cast<const float4*>(A + (size_t)row0 * HD);
    #pragma unroll
    for (int q = 0; q < 12; ++q) {
        const int f4 = t + q * 256;
        const int r = f4 / 48, c = f4 % 48;
        *reinterpret_cast<float4*>(&xsf[r][c * 4]) = ap[f4];
    }

    const int tr = t >> 4;
    const int tc = t & 15;
    float acc[4][12];
    #pragma unroll
    for (int i = 0; i < 4; ++i)
        #pragma unroll
        for (int j = 0; j < 12; ++j) acc[i][j] = 0.f;

    for (int kc = 0; kc < 6; ++kc) {
        __syncthreads();
        {
            const float4* wp = reinterpret_cast<const float4*>(W + kc * 32 * HD);
            float4* wsp = reinterpret_cast<float4*>(&wchunk[0][0]);
            #pragma unroll
            for (int q = 0; q < 6; ++q) wsp[t + q * 256] = wp[t + q * 256];
        }
        __syncthreads();
        #pragma unroll 4
        for (int k = 0; k < 32; ++k) {
            const int kg = kc * 32 + k;
            float xv[4];
            #pragma unroll
            for (int i = 0; i < 4; ++i) xv[i] = xsf[tr * 4 + i][kg];
            float wv[12];
            #pragma unroll
            for (int j4 = 0; j4 < 3; ++j4)
                *reinterpret_cast<float4*>(&wv[j4 * 4]) =
                    *reinterpret_cast<const float4*>(&wchunk[k][tc * 12 + j4 * 4]);
            #pragma unroll
            for (int i = 0; i < 4; ++i)
                #pragma unroll
                for (int j = 0; j < 12; ++j)
                    acc[i][j] = fmaf(xv[i], wv[j], acc[i][j]);
        }
    }

    float bb[12];
    #pragma unroll
    for (int j = 0; j < 12; ++j) bb[j] = bias[tc * 12 + j];

    #pragma unroll
    for (int i = 0; i < 4; ++i) {
        float* o = out + (size_t)(row0 + tr * 4 + i) * HD + tc * 12;
        #pragma unroll
        for (int j4 = 0; j4 < 3; ++j4) {
            float4 v;
            v.x = acc[i][j4 * 4 + 0] + bb[j4 * 4 + 0];
            v.y = acc[i][j4 * 4 + 1] + bb[j4 * 4 + 1];
            v.z = acc[i][j4 * 4 + 2] + bb[j4 * 4 + 2];
            v.w = acc[i][j4 * 4 + 3] + bb[j4 * 4 + 3];
            *reinterpret_cast<float4*>(o + j4 * 4) = v;
        }
    }
}

extern "C" void kernel_launch(void* const* d_in, const int* in_sizes, int n_in,
                              void* d_out, int out_size, void* d_ws, size_t ws_size,
                              hipStream_t stream)
{
    const float* feat = (const float*)d_in[0];
    const float* pos  = (const float*)d_in[1];
    const int*   sup  = (const int*)d_in[2];
    const int*   src  = (const int*)d_in[4];
    const float* Win  = (const float*)d_in[6];
    const float* bin  = (const float*)d_in[7];
    const float* W1   = (const float*)d_in[8];   // [384,192]
    const float* b1   = (const float*)d_in[9];
    const float* W2   = (const float*)d_in[10];  // [192,192]
    const float* b2   = (const float*)d_in[11];

    char* ws = (char*)d_ws;
    unsigned short* Wt   = (unsigned short*)ws;              //  73728 B
    unsigned short* Wb   = (unsigned short*)(ws + 73728);    //  73728 B
    float*          Wint = (float*)(ws + 147456);            //  12288 B
    unsigned short* x    = (unsigned short*)(ws + 159744);   // 100663296 B (x, then a in-place)
    char*           C    = ws + 159744 + 100663296;          //  12582912 B
    float* out = (float*)d_out;

    prep_kernel<<<300, 256, 0, stream>>>(W1, Win, Wt, Wb, Wint);
    // x (bf16, chunk-swizzled)
    xcomp_kernel<<<N_NODES / 64, 256, 0, stream>>>(feat, pos, Wint, bin, x);
    // b = x[sup] @ W1_bot + b1 -> bf16 rows in C (stride 384 elems)
    agemm_kernel<true><<<N_SUP / 64, 256, 0, stream>>>(
        x, sup, Wb, b1, (unsigned short*)C, 384, 1);
    // a = x @ W1_top -> plain bf16, in place over x
    agemm_kernel<false><<<N_NODES / 256, 256, 0, stream>>>(
        x, nullptr, Wt, nullptr, x, HD, 4);
    // g = segment-mean(gelu(a[src] + b[dst])) -> f32 in place over C
    pool_kernel<<<N_SUP / 4, 192, 0, stream>>>(x, (const unsigned short*)C, src, (float*)C);
    // out = g @ W2 + b2
    gemm192_kernel<<<N_SUP / 64, 256, 0, stream>>>((const float*)C, W2, b2, out);
}

// Round 6
// 254.306 us; speedup vs baseline: 1.9697x; 1.0279x over previous
//
#include <hip/hip_runtime.h>
#include <hip/hip_bf16.h>

// SupernodePooling pipeline:
//   prep:   Wt/Wb = bf16(W1_top/bot)^T, Wint = Win^T
//   xcomp:  x = feat@W_in + b_in + sincos(pos) -> bf16, chunk-XOR-swizzled [N,192]
//   agemm<true>:  b = x[sup] @ W1_bot + b1 -> bf16 rows interleaved in C (stride 384)
//   agemm<false>: a = x @ W1_top -> bf16 [N,192] plain, IN PLACE over x buffer
//   pool:   g[s] = mean_{32 edges} gelu(a[src]+b[s]) -> f32 in place over C
//   gemm192: out = g @ W2 + b2
// Identities: concat-GEMM splits; segment-mean commutes with W2; seg[e]=e/32.
// NOTE: launch_bounds (256,2) on register-heavy kernels — tighter caps spilled
// win[]/bfr[]/acc[] to scratch (round-4 post-mortem: 466 MB of spill traffic).

#define HD 192
#define INF 16
#define N_NODES 262144
#define N_SUP 16384
#define ROWB 384      // bytes per 192-bf16 row

typedef __attribute__((ext_vector_type(8))) short bf16x8;
typedef __attribute__((ext_vector_type(4))) float f32x4;

__device__ __forceinline__ unsigned f2bf(float f) {
    unsigned x = __float_as_uint(f);
    return (x + 0x7fffu + ((x >> 16) & 1u)) >> 16;   // RNE
}
__device__ __forceinline__ float bf2f(unsigned short u) {
    return __uint_as_float(((unsigned)u) << 16);
}
__device__ __forceinline__ void gload16(const void* g, void* l) {
    __builtin_amdgcn_global_load_lds(
        (const __attribute__((address_space(1))) unsigned int*)g,
        (__attribute__((address_space(3))) unsigned int*)l, 16, 0, 0);
}
// tanh-form GELU folded into accumulator: acc += gelu(v).
// max dev from exact erf-GELU ~5e-4 (validated r4/r5, absmax 0.0156)
__device__ __forceinline__ void gelu_acc(float v, float& acc) {
    const float m   = v * fmaf(v * v, -0.1029392f, -2.3021178f);
    const float den = 1.f + exp2f(m);
    const float r   = __builtin_amdgcn_rcpf(den);
    acc = fmaf(v, r, acc);
}

// ---------------------------------------------------------------------------
__global__ void prep_kernel(const float* __restrict__ W1,
                            const float* __restrict__ Win,
                            unsigned short* __restrict__ Wt,
                            unsigned short* __restrict__ Wb,
                            float* __restrict__ Wint)
{
    const int i = blockIdx.x * 256 + threadIdx.x;
    if (i < 36864) {
        const int n = i / HD, k = i % HD;
        Wt[i] = (unsigned short)f2bf(W1[k * HD + n]);
    } else if (i < 73728) {
        const int j = i - 36864;
        const int n = j / HD, k = j % HD;
        Wb[j] = (unsigned short)f2bf(W1[(size_t)(HD + k) * HD + n]);
    } else if (i < 76800) {
        const int j = i - 73728;
        const int c = j / INF, k = j % INF;
        Wint[j] = Win[k * HD + c];
    }
}

// ---------------------------------------------------------------------------
// xcomp: x[n][c] = dot(feat[n], Win[:,c]) + bin[c] + sin/cos(pos[n][c/64]*om)
// Output bf16, chunk-swizzled: 16B chunk c of row r stored at chunk c^(r&7).
// 4 groups of 64 rows per block (amortizes the per-lane weight preload 4x).
// Wave-local (no barriers). Lane l owns cols {l, l+64, l+128}.
// ---------------------------------------------------------------------------
__global__ __launch_bounds__(256, 2)
void xcomp_kernel(const float* __restrict__ feat,
                  const float* __restrict__ pos,
                  const float* __restrict__ Wint,   // [192 c][16 k]
                  const float* __restrict__ bin,
                  unsigned short* __restrict__ xswz)
{
    __shared__ __align__(16) float feat_s[4][256];             // 16 rows x 16 per wave
    __shared__ float pos_s[4][48];
    __shared__ __align__(16) unsigned short dstg[4][16 * HD];  // 16 rows per wave

    const int t = threadIdx.x, w = t >> 6, l = t & 63;

    float win[3][INF];
    #pragma unroll
    for (int d = 0; d < 3; ++d)
        #pragma unroll
        for (int q = 0; q < 4; ++q)
            *reinterpret_cast<float4*>(&win[d][q * 4]) =
                *reinterpret_cast<const float4*>(Wint + (size_t)(l + 64 * d) * INF + q * 4);
    float bcol[3];
    #pragma unroll
    for (int d = 0; d < 3; ++d) bcol[d] = bin[l + 64 * d];
    const float om = exp2f(-(float)(l & 31) * 0.41524101186098287f);
    const float phase = (l < 32) ? 0.f : 1.57079632679f;   // cos = sin(+pi/2)

    for (int gg = 0; gg < 4; ++gg) {
        const int row0 = blockIdx.x * 256 + gg * 64 + w * 16;

        // stage 16 rows of feat/pos (wave-local)
        {
            const float4 f4 = *reinterpret_cast<const float4*>(
                feat + (size_t)(row0 + (l >> 2)) * INF + (l & 3) * 4);
            *reinterpret_cast<float4*>(&feat_s[w][(l >> 2) * 16 + (l & 3) * 4]) = f4;
            if (l < 48) pos_s[w][l] = pos[(size_t)row0 * 3 + l];
        }

        for (int r = 0; r < 16; ++r) {
            float fr[INF];
            #pragma unroll
            for (int q = 0; q < 4; ++q)
                *reinterpret_cast<float4*>(&fr[q * 4]) =
                    *reinterpret_cast<const float4*>(&feat_s[w][r * 16 + q * 4]);
            #pragma unroll
            for (int d = 0; d < 3; ++d) {
                const float pe = __sinf(fmaf(pos_s[w][r * 3 + d], om, phase));
                float acc = bcol[d] + pe;
                #pragma unroll
                for (int k = 0; k < INF; ++k) acc = fmaf(fr[k], win[d][k], acc);
                dstg[w][r * HD + l + 64 * d] = (unsigned short)f2bf(acc);
            }
        }

        // readback + swizzled coalesced store (wave-local)
        #pragma unroll
        for (int q = 0; q < 6; ++q) {
            const int id = q * 64 + l;          // 0..383
            const int rl = id / 24, c = id % 24;
            const bf16x8 v = *reinterpret_cast<const bf16x8*>(&dstg[w][rl * HD + c * 8]);
            *reinterpret_cast<bf16x8*>((char*)xswz +
                (size_t)(row0 + rl) * ROWB + ((c ^ (rl & 7)) * 16)) = v;
        }
    }
}

// ---------------------------------------------------------------------------
// agemm: out = bf16( X @ Wt^T (+bias) ), X = swizzled bf16 [.,192], K=192.
// 4 waves: wave w -> cols [w*48,w*48+48). global_load_lds staging, 2-buf LDS,
// dstg aliases consumed buffer. A-frag reads XOR-swizzled -> bank-balanced.
// ---------------------------------------------------------------------------
template<bool GATHER>
__global__ __launch_bounds__(256, 2)
void agemm_kernel(const unsigned short* __restrict__ xswz,
                  const int* __restrict__ gidx,
                  const unsigned short* __restrict__ Wt,   // [192 n][192 k]
                  const float* __restrict__ bias,
                  unsigned short* __restrict__ outp,
                  const int out_stride,                    // elems
                  const int ntiles)
{
    __shared__ __align__(16) unsigned short xbuf[2][64 * HD];  // 2 x 24576 B
    __shared__ int nid[64];

    const int t = threadIdx.x, w = t >> 6, l = t & 63;

    bf16x8 bfr[3][6];
    #pragma unroll
    for (int ct = 0; ct < 3; ++ct) {
        const int col = w * 48 + ct * 16 + (l & 15);
        const unsigned short* wp = Wt + (size_t)col * HD + (l >> 4) * 8;
        #pragma unroll
        for (int ks = 0; ks < 6; ++ks)
            bfr[ct][ks] = *reinterpret_cast<const bf16x8*>(wp + ks * 32);
    }
    float bias_c[3] = {0.f, 0.f, 0.f};
    if (GATHER) {
        #pragma unroll
        for (int ct = 0; ct < 3; ++ct) bias_c[ct] = bias[w * 48 + ct * 16 + (l & 15)];
        if (t < 64) nid[t] = gidx[blockIdx.x * 64 + t];
        __syncthreads();
    }

    auto STAGE = [&](int tile, int buf) {
        char* lbase = (char*)&xbuf[buf][0];
        if constexpr (GATHER) {
            #pragma unroll
            for (int i = 0; i < 6; ++i) {
                const int slot = w * 64 + i * 256 + l;
                const int r = slot / 24, p = slot % 24;
                const int node = nid[r];
                const char* src = (const char*)xswz + (size_t)node * ROWB +
                                  (((p ^ (r & 7)) ^ (node & 7)) * 16);
                gload16(src, lbase + w * 1024 + i * 4096);
            }
        } else {
            const char* gb = (const char*)xswz +
                             (size_t)(blockIdx.x * ntiles + tile) * 64 * ROWB;
            #pragma unroll
            for (int i = 0; i < 6; ++i)
                gload16(gb + w * 1024 + i * 4096 + l * 16, lbase + w * 1024 + i * 4096);
        }
    };

    STAGE(0, 0);
    __syncthreads();

    for (int tt = 0; tt < ntiles; ++tt) {
        const int cur = tt & 1;
        if (tt + 1 < ntiles) STAGE(tt + 1, cur ^ 1);

        f32x4 acc[4][3];
        #pragma unroll
        for (int rt = 0; rt < 4; ++rt)
            #pragma unroll
            for (int ct = 0; ct < 3; ++ct)
                acc[rt][ct] = (f32x4){0.f, 0.f, 0.f, 0.f};

        const char* xb = (const char*)&xbuf[cur][0];
        #pragma unroll
        for (int ks = 0; ks < 6; ++ks) {
            bf16x8 af[4];
            #pragma unroll
            for (int rt = 0; rt < 4; ++rt) {
                const int row = rt * 16 + (l & 15);
                const int p = (ks * 4 + (l >> 4)) ^ (l & 7);   // row&7 == l&7
                af[rt] = *reinterpret_cast<const bf16x8*>(xb + row * ROWB + p * 16);
            }
            #pragma unroll
            for (int rt = 0; rt < 4; ++rt)
                #pragma unroll
                for (int ct = 0; ct < 3; ++ct)
                    acc[rt][ct] = __builtin_amdgcn_mfma_f32_16x16x32_bf16(
                        af[rt], bfr[ct][ks], acc[rt][ct], 0, 0, 0);
        }
        __syncthreads();   // vmcnt(0): next tile staged; all reads of cur done

        // D (+bias) -> dstg (= xbuf[cur]), XOR-swizzled; wave-local column band
        char* db = (char*)&xbuf[cur][0];
        #pragma unroll
        for (int rt = 0; rt < 4; ++rt)
            #pragma unroll
            for (int ct = 0; ct < 3; ++ct) {
                const int col = w * 48 + ct * 16 + (l & 15);
                const int ch = col >> 3, off = col & 7;
                #pragma unroll
                for (int j = 0; j < 4; ++j) {
                    const int row = rt * 16 + (l >> 4) * 4 + j;
                    *reinterpret_cast<unsigned short*>(
                        db + row * ROWB + ((ch ^ (row & 7)) * 16) + off * 2) =
                        (unsigned short)f2bf(acc[rt][ct][j] + bias_c[ct]);
                }
            }
        // readback + plain store (wave-local band: chunks [w*6, w*6+6))
        const size_t orow0 = GATHER ? (size_t)blockIdx.x * 64
                                    : (size_t)(blockIdx.x * ntiles + tt) * 64;
        #pragma unroll
        for (int q = 0; q < 6; ++q) {
            const int id = q * 64 + l;      // 0..383
            const int rid = id / 6, cc = id % 6;
            const int c = w * 6 + cc;
            const bf16x8 v = *reinterpret_cast<const bf16x8*>(
                db + rid * ROWB + ((c ^ (rid & 7)) * 16));
            *reinterpret_cast<bf16x8*>(outp + (orow0 + rid) * out_stride + c * 8) = v;
        }
        __syncthreads();   // dstg reads done before next STAGE overwrites
    }
}

// ---------------------------------------------------------------------------
// pool: g[s] = (1/32) * sum_e gelu(a[src]+b[s]); b bf16 rows at stride 384
// elems in C, g f32 overwrites same rows. 4 supernodes x 48 thr.
// v2: 8-deep explicit load batching (keeps 8 global_load_dwordx2 in flight;
// r5's rolled loop at VGPR=20 exposed gather latency every iteration),
// 32-bit byte offsets in LDS, rcp+fmaf-folded gelu.
// ---------------------------------------------------------------------------
__global__ __launch_bounds__(192)
void pool_kernel(const unsigned short* __restrict__ a,   // [N,192] bf16 plain
                 const unsigned short* __restrict__ bC,
                 const int* __restrict__ src_idx,
                 float* __restrict__ g)
{
    __shared__ int sA[128];          // byte offsets: src*384
    const int t = threadIdx.x;
    if (t < 128) sA[t] = src_idx[(size_t)blockIdx.x * 128 + t] * ROWB;
    __syncthreads();

    const int sl = t / 48;
    const int c4 = t % 48;
    const size_t s = (size_t)blockIdx.x * 4 + sl;
    const int* sp = sA + sl * 32;
    const int cb = c4 * 8;           // byte offset within row

    const ushort4 bu = *reinterpret_cast<const ushort4*>(bC + s * 384 + c4 * 4);
    const float b0 = bf2f(bu.x), b1v = bf2f(bu.y), b2v = bf2f(bu.z), b3v = bf2f(bu.w);

    const char* ab = (const char*)a;
    float a0 = 0.f, a1 = 0.f, a2 = 0.f, a3 = 0.f;
    #pragma unroll
    for (int e0 = 0; e0 < 32; e0 += 8) {
        uint2 u[8];
        #pragma unroll
        for (int i = 0; i < 8; ++i)
            u[i] = *reinterpret_cast<const uint2*>(ab + (size_t)(unsigned)(sp[e0 + i] + cb));
        #pragma unroll
        for (int i = 0; i < 8; ++i) {
            gelu_acc(__uint_as_float(u[i].x << 16)          + b0,  a0);
            gelu_acc(__uint_as_float(u[i].x & 0xffff0000u)  + b1v, a1);
            gelu_acc(__uint_as_float(u[i].y << 16)          + b2v, a2);
            gelu_acc(__uint_as_float(u[i].y & 0xffff0000u)  + b3v, a3);
        }
    }
    __syncthreads();   // all b reads done before aliased g writes
    float4 r;
    r.x = a0 * 0.03125f; r.y = a1 * 0.03125f; r.z = a2 * 0.03125f; r.w = a3 * 0.03125f;
    *reinterpret_cast<float4*>(g + s * HD + c4 * 4) = r;
}

// ---------------------------------------------------------------------------
// out = A[rows,192] @ W[192,192] + bias   (f32)
// ---------------------------------------------------------------------------
__global__ __launch_bounds__(256, 2)
void gemm192_kernel(const float* __restrict__ A,
                    const float* __restrict__ W,
                    const float* __restrict__ bias,
                    float* __restrict__ out)
{
    __shared__ float xsf[64][196];
    __shared__ float wchunk[32][HD];
    const int t    = threadIdx.x;
    const int row0 = blockIdx.x * 64;

    const float4* ap = reinterpret_cast<const float4*>(A + (size_t)row0 * HD);
    #pragma unroll
    for (int q = 0; q < 12; ++q) {
        const int f4 = t + q * 256;
        const int r = f4 / 48, c = f4 % 48;
        *reinterpret_cast<float4*>(&xsf[r][c * 4]) = ap[f4];
    }

    const int tr = t >> 4;
    const int tc = t & 15;
    float acc[4][12];
    #pragma unroll
    for (int i = 0; i < 4; ++i)
        #pragma unroll
        for (int j = 0; j < 12; ++j) acc[i][j] = 0.f;

    for (int kc = 0; kc < 6; ++kc) {
        __syncthreads();
        {
            const float4* wp = reinterpret_cast<const float4*>(W + kc * 32 * HD);
            float4* wsp = reinterpret_cast<float4*>(&wchunk[0][0]);
            #pragma unroll
            for (int q = 0; q < 6; ++q) wsp[t + q * 256] = wp[t + q * 256];
        }
        __syncthreads();
        #pragma unroll 4
        for (int k = 0; k < 32; ++k) {
            const int kg = kc * 32 + k;
            float xv[4];
            #pragma unroll
            for (int i = 0; i < 4; ++i) xv[i] = xsf[tr * 4 + i][kg];
            float wv[12];
            #pragma unroll
            for (int j4 = 0; j4 < 3; ++j4)
                *reinterpret_cast<float4*>(&wv[j4 * 4]) =
                    *reinterpret_cast<const float4*>(&wchunk[k][tc * 12 + j4 * 4]);
            #pragma unroll
            for (int i = 0; i < 4; ++i)
                #pragma unroll
                for (int j = 0; j < 12; ++j)
                    acc[i][j] = fmaf(xv[i], wv[j], acc[i][j]);
        }
    }

    float bb[12];
    #pragma unroll
    for (int j = 0; j < 12; ++j) bb[j] = bias[tc * 12 + j];

    #pragma unroll
    for (int i = 0; i < 4; ++i) {
        float* o = out + (size_t)(row0 + tr * 4 + i) * HD + tc * 12;
        #pragma unroll
        for (int j4 = 0; j4 < 3; ++j4) {
            float4 v;
            v.x = acc[i][j4 * 4 + 0] + bb[j4 * 4 + 0];
            v.y = acc[i][j4 * 4 + 1] + bb[j4 * 4 + 1];
            v.z = acc[i][j4 * 4 + 2] + bb[j4 * 4 + 2];
            v.w = acc[i][j4 * 4 + 3] + bb[j4 * 4 + 3];
            *reinterpret_cast<float4*>(o + j4 * 4) = v;
        }
    }
}

extern "C" void kernel_launch(void* const* d_in, const int* in_sizes, int n_in,
                              void* d_out, int out_size, void* d_ws, size_t ws_size,
                              hipStream_t stream)
{
    const float* feat = (const float*)d_in[0];
    const float* pos  = (const float*)d_in[1];
    const int*   sup  = (const int*)d_in[2];
    const int*   src  = (const int*)d_in[4];
    const float* Win  = (const float*)d_in[6];
    const float* bin  = (const float*)d_in[7];
    const float* W1   = (const float*)d_in[8];   // [384,192]
    const float* b1   = (const float*)d_in[9];
    const float* W2   = (const float*)d_in[10];  // [192,192]
    const float* b2   = (const float*)d_in[11];

    char* ws = (char*)d_ws;
    unsigned short* Wt   = (unsigned short*)ws;              //  73728 B
    unsigned short* Wb   = (unsigned short*)(ws + 73728);    //  73728 B
    float*          Wint = (float*)(ws + 147456);            //  12288 B
    unsigned short* x    = (unsigned short*)(ws + 159744);   // 100663296 B (x, then a in-place)
    char*           C    = ws + 159744 + 100663296;          //  12582912 B
    float* out = (float*)d_out;

    prep_kernel<<<300, 256, 0, stream>>>(W1, Win, Wt, Wb, Wint);
    // x (bf16, chunk-swizzled), 1024 blocks x 256 rows
    xcomp_kernel<<<N_NODES / 256, 256, 0, stream>>>(feat, pos, Wint, bin, x);
    // b = x[sup] @ W1_bot + b1 -> bf16 rows in C (stride 384 elems)
    agemm_kernel<true><<<N_SUP / 64, 256, 0, stream>>>(
        x, sup, Wb, b1, (unsigned short*)C, 384, 1);
    // a = x @ W1_top -> plain bf16, in place over x
    agemm_kernel<false><<<N_NODES / 256, 256, 0, stream>>>(
        x, nullptr, Wt, nullptr, x, HD, 4);
    // g = segment-mean(gelu(a[src] + b[dst])) -> f32 in place over C
    pool_kernel<<<N_SUP / 4, 192, 0, stream>>>(x, (const unsigned short*)C, src, (float*)C);
    // out = g @ W2 + b2
    gemm192_kernel<<<N_SUP / 64, 256, 0, stream>>>((const float*)C, W2, b2, out);
}

// Round 8
// 248.878 us; speedup vs baseline: 2.0126x; 1.0218x over previous
//
#include <hip/hip_runtime.h>
#include <hip/hip_bf16.h>

// SupernodePooling pipeline (round 7 resubmit — r7 bench was an infra timeout):
//   prep:    Wt/Wb = bf16(W1_top/bot)^T, Wint = Win^T
//   xcomp:   x = feat@W_in + b_in + sincos(pos) -> bf16, chunk-XOR-swizzled [N,192]
//   agemm<true>: b = x[sup] @ W1_bot + b1 -> bf16 rows in C (stride 384 elems)
//   edgepool: per 64-edge tile: gather x[src] -> MFMA @ W1_top -> +b[s] -> gelu
//             -> sum 32 rows/supernode -> g[s] f32, in place over C
//   gemm192: out = g @ W2 + b2
// Identities: concat-GEMM splits; segment-mean commutes with W2; seg[e]=e/32.
// NOTE: launch_bounds (256,2) on register-heavy kernels — tighter caps spilled
// win[]/bfr[]/acc[] to scratch (round-4 post-mortem: 466 MB of spill traffic).

#define HD 192
#define INF 16
#define N_NODES 262144
#define N_SUP 16384
#define ROWB 384      // bytes per 192-bf16 row
#define EP_TILES 4    // 64-edge tiles per edgepool block

typedef __attribute__((ext_vector_type(8))) short bf16x8;
typedef __attribute__((ext_vector_type(4))) float f32x4;

__device__ __forceinline__ unsigned f2bf(float f) {
    unsigned x = __float_as_uint(f);
    return (x + 0x7fffu + ((x >> 16) & 1u)) >> 16;   // RNE
}
__device__ __forceinline__ float bf2f(unsigned short u) {
    return __uint_as_float(((unsigned)u) << 16);
}
__device__ __forceinline__ void gload16(const void* g, void* l) {
    __builtin_amdgcn_global_load_lds(
        (const __attribute__((address_space(1))) unsigned int*)g,
        (__attribute__((address_space(3))) unsigned int*)l, 16, 0, 0);
}
// tanh-form GELU folded into accumulator: acc += gelu(v).
// max dev from exact erf-GELU ~5e-4 (validated r4-r6, absmax 0.0156)
__device__ __forceinline__ void gelu_acc(float v, float& acc) {
    const float m   = v * fmaf(v * v, -0.1029392f, -2.3021178f);
    const float den = 1.f + exp2f(m);
    const float r   = __builtin_amdgcn_rcpf(den);
    acc = fmaf(v, r, acc);
}

// ---------------------------------------------------------------------------
__global__ void prep_kernel(const float* __restrict__ W1,
                            const float* __restrict__ Win,
                            unsigned short* __restrict__ Wt,
                            unsigned short* __restrict__ Wb,
                            float* __restrict__ Wint)
{
    const int i = blockIdx.x * 256 + threadIdx.x;
    if (i < 36864) {
        const int n = i / HD, k = i % HD;
        Wt[i] = (unsigned short)f2bf(W1[k * HD + n]);
    } else if (i < 73728) {
        const int j = i - 36864;
        const int n = j / HD, k = j % HD;
        Wb[j] = (unsigned short)f2bf(W1[(size_t)(HD + k) * HD + n]);
    } else if (i < 76800) {
        const int j = i - 73728;
        const int c = j / INF, k = j % INF;
        Wint[j] = Win[k * HD + c];
    }
}

// ---------------------------------------------------------------------------
// xcomp: x[n][c] = dot(feat[n], Win[:,c]) + bin[c] + sin/cos(pos[n][c/64]*om)
// Output bf16, chunk-swizzled: 16B chunk c of row r stored at chunk c^(r&7).
// 4 groups of 64 rows per block. Wave-local (no barriers).
// ---------------------------------------------------------------------------
__global__ __launch_bounds__(256, 2)
void xcomp_kernel(const float* __restrict__ feat,
                  const float* __restrict__ pos,
                  const float* __restrict__ Wint,   // [192 c][16 k]
                  const float* __restrict__ bin,
                  unsigned short* __restrict__ xswz)
{
    __shared__ __align__(16) float feat_s[4][256];             // 16 rows x 16 per wave
    __shared__ float pos_s[4][48];
    __shared__ __align__(16) unsigned short dstg[4][16 * HD];  // 16 rows per wave

    const int t = threadIdx.x, w = t >> 6, l = t & 63;

    float win[3][INF];
    #pragma unroll
    for (int d = 0; d < 3; ++d)
        #pragma unroll
        for (int q = 0; q < 4; ++q)
            *reinterpret_cast<float4*>(&win[d][q * 4]) =
                *reinterpret_cast<const float4*>(Wint + (size_t)(l + 64 * d) * INF + q * 4);
    float bcol[3];
    #pragma unroll
    for (int d = 0; d < 3; ++d) bcol[d] = bin[l + 64 * d];
    const float om = exp2f(-(float)(l & 31) * 0.41524101186098287f);
    const float phase = (l < 32) ? 0.f : 1.57079632679f;   // cos = sin(+pi/2)

    for (int gg = 0; gg < 4; ++gg) {
        const int row0 = blockIdx.x * 256 + gg * 64 + w * 16;

        {
            const float4 f4 = *reinterpret_cast<const float4*>(
                feat + (size_t)(row0 + (l >> 2)) * INF + (l & 3) * 4);
            *reinterpret_cast<float4*>(&feat_s[w][(l >> 2) * 16 + (l & 3) * 4]) = f4;
            if (l < 48) pos_s[w][l] = pos[(size_t)row0 * 3 + l];
        }

        for (int r = 0; r < 16; ++r) {
            float fr[INF];
            #pragma unroll
            for (int q = 0; q < 4; ++q)
                *reinterpret_cast<float4*>(&fr[q * 4]) =
                    *reinterpret_cast<const float4*>(&feat_s[w][r * 16 + q * 4]);
            #pragma unroll
            for (int d = 0; d < 3; ++d) {
                const float pe = __sinf(fmaf(pos_s[w][r * 3 + d], om, phase));
                float acc = bcol[d] + pe;
                #pragma unroll
                for (int k = 0; k < INF; ++k) acc = fmaf(fr[k], win[d][k], acc);
                dstg[w][r * HD + l + 64 * d] = (unsigned short)f2bf(acc);
            }
        }

        #pragma unroll
        for (int q = 0; q < 6; ++q) {
            const int id = q * 64 + l;          // 0..383
            const int rl = id / 24, c = id % 24;
            const bf16x8 v = *reinterpret_cast<const bf16x8*>(&dstg[w][rl * HD + c * 8]);
            *reinterpret_cast<bf16x8*>((char*)xswz +
                (size_t)(row0 + rl) * ROWB + ((c ^ (rl & 7)) * 16)) = v;
        }
    }
}

// ---------------------------------------------------------------------------
// agemm<GATHER=true>: b = bf16( x[gidx] @ Wt^T + bias ), K=192, 64 rows/block.
// ---------------------------------------------------------------------------
template<bool GATHER>
__global__ __launch_bounds__(256, 2)
void agemm_kernel(const unsigned short* __restrict__ xswz,
                  const int* __restrict__ gidx,
                  const unsigned short* __restrict__ Wt,   // [192 n][192 k]
                  const float* __restrict__ bias,
                  unsigned short* __restrict__ outp,
                  const int out_stride,                    // elems
                  const int ntiles)
{
    __shared__ __align__(16) unsigned short xbuf[2][64 * HD];  // 2 x 24576 B
    __shared__ int nid[64];

    const int t = threadIdx.x, w = t >> 6, l = t & 63;

    bf16x8 bfr[3][6];
    #pragma unroll
    for (int ct = 0; ct < 3; ++ct) {
        const int col = w * 48 + ct * 16 + (l & 15);
        const unsigned short* wp = Wt + (size_t)col * HD + (l >> 4) * 8;
        #pragma unroll
        for (int ks = 0; ks < 6; ++ks)
            bfr[ct][ks] = *reinterpret_cast<const bf16x8*>(wp + ks * 32);
    }
    float bias_c[3] = {0.f, 0.f, 0.f};
    if (GATHER) {
        #pragma unroll
        for (int ct = 0; ct < 3; ++ct) bias_c[ct] = bias[w * 48 + ct * 16 + (l & 15)];
        if (t < 64) nid[t] = gidx[blockIdx.x * 64 + t];
        __syncthreads();
    }

    auto STAGE = [&](int tile, int buf) {
        char* lbase = (char*)&xbuf[buf][0];
        if constexpr (GATHER) {
            #pragma unroll
            for (int i = 0; i < 6; ++i) {
                const int slot = w * 64 + i * 256 + l;
                const int r = slot / 24, p = slot % 24;
                const int node = nid[r];
                const char* src = (const char*)xswz + (size_t)node * ROWB +
                                  (((p ^ (r & 7)) ^ (node & 7)) * 16);
                gload16(src, lbase + w * 1024 + i * 4096);
            }
        } else {
            const char* gb = (const char*)xswz +
                             (size_t)(blockIdx.x * ntiles + tile) * 64 * ROWB;
            #pragma unroll
            for (int i = 0; i < 6; ++i)
                gload16(gb + w * 1024 + i * 4096 + l * 16, lbase + w * 1024 + i * 4096);
        }
    };

    STAGE(0, 0);
    __syncthreads();

    for (int tt = 0; tt < ntiles; ++tt) {
        const int cur = tt & 1;
        if (tt + 1 < ntiles) STAGE(tt + 1, cur ^ 1);

        f32x4 acc[4][3];
        #pragma unroll
        for (int rt = 0; rt < 4; ++rt)
            #pragma unroll
            for (int ct = 0; ct < 3; ++ct)
                acc[rt][ct] = (f32x4){0.f, 0.f, 0.f, 0.f};

        const char* xb = (const char*)&xbuf[cur][0];
        #pragma unroll
        for (int ks = 0; ks < 6; ++ks) {
            bf16x8 af[4];
            #pragma unroll
            for (int rt = 0; rt < 4; ++rt) {
                const int row = rt * 16 + (l & 15);
                const int p = (ks * 4 + (l >> 4)) ^ (l & 7);   // row&7 == l&7
                af[rt] = *reinterpret_cast<const bf16x8*>(xb + row * ROWB + p * 16);
            }
            #pragma unroll
            for (int rt = 0; rt < 4; ++rt)
                #pragma unroll
                for (int ct = 0; ct < 3; ++ct)
                    acc[rt][ct] = __builtin_amdgcn_mfma_f32_16x16x32_bf16(
                        af[rt], bfr[ct][ks], acc[rt][ct], 0, 0, 0);
        }
        __syncthreads();   // next tile staged; all LDS reads of cur done

        char* db = (char*)&xbuf[cur][0];
        #pragma unroll
        for (int rt = 0; rt < 4; ++rt)
            #pragma unroll
            for (int ct = 0; ct < 3; ++ct) {
                const int col = w * 48 + ct * 16 + (l & 15);
                const int ch = col >> 3, off = col & 7;
                #pragma unroll
                for (int j = 0; j < 4; ++j) {
                    const int row = rt * 16 + (l >> 4) * 4 + j;
                    *reinterpret_cast<unsigned short*>(
                        db + row * ROWB + ((ch ^ (row & 7)) * 16) + off * 2) =
                        (unsigned short)f2bf(acc[rt][ct][j] + bias_c[ct]);
                }
            }
        const size_t orow0 = GATHER ? (size_t)blockIdx.x * 64
                                    : (size_t)(blockIdx.x * ntiles + tt) * 64;
        #pragma unroll
        for (int q = 0; q < 6; ++q) {
            const int id = q * 64 + l;      // 0..383
            const int rid = id / 6, cc = id % 6;
            const int c = w * 6 + cc;
            const bf16x8 v = *reinterpret_cast<const bf16x8*>(
                db + rid * ROWB + ((c ^ (rid & 7)) * 16));
            *reinterpret_cast<bf16x8*>(outp + (orow0 + rid) * out_stride + c * 8) = v;
        }
        __syncthreads();
    }
}

// ---------------------------------------------------------------------------
// edgepool: per 64-edge tile (2 supernodes):
//   stage x[src[e]] (gathered, pre-swizzled) -> LDS
//   MFMA: [64,192] @ W1_top^T -> acc (f32)
//   v = acc + b[s][col] (b bf16 from C);  part = sum_{8 own rows} gelu(v)
//   shfl_xor(16)+shfl_xor(32) completes 32-row column sum -> g[s] = part/32 (f32, over C)
// D layout: col=l&15, row=rt*16+(l>>4)*4+j -> rt<2 is supernode 0, rt>=2 is 1;
// lanes {l, l+16, l+32, l+48} share a column and partition its 32 rows.
// ---------------------------------------------------------------------------
__global__ __launch_bounds__(256, 2)
void edgepool_kernel(const unsigned short* __restrict__ xswz,
                     const int* __restrict__ src_idx,
                     const unsigned short* __restrict__ Wt,   // W1_top^T [192 n][192 k]
                     const unsigned short* __restrict__ bC,   // bf16 rows, stride 384 elems
                     float* __restrict__ g)                   // f32 rows, stride 192 (same mem)
{
    __shared__ __align__(16) unsigned short xbuf[2][64 * HD];  // 2 x 24576 B

    const int t = threadIdx.x, w = t >> 6, l = t & 63;

    bf16x8 bfr[3][6];
    #pragma unroll
    for (int ct = 0; ct < 3; ++ct) {
        const int col = w * 48 + ct * 16 + (l & 15);
        const unsigned short* wp = Wt + (size_t)col * HD + (l >> 4) * 8;
        #pragma unroll
        for (int ks = 0; ks < 6; ++ks)
            bfr[ct][ks] = *reinterpret_cast<const bf16x8*>(wp + ks * 32);
    }

    auto STAGE = [&](int tile, int buf) {
        char* lbase = (char*)&xbuf[buf][0] + w * 1024;
        const int* se = src_idx + (size_t)(blockIdx.x * EP_TILES + tile) * 64;
        #pragma unroll
        for (int i = 0; i < 6; ++i) {
            const int slot = w * 64 + i * 256 + l;
            const int r = slot / 24, p = slot % 24;
            const int node = se[r];
            const char* src = (const char*)xswz + (size_t)node * ROWB +
                              (((p ^ (r & 7)) ^ (node & 7)) * 16);
            gload16(src, lbase + i * 4096);
        }
    };

    STAGE(0, 0);
    __syncthreads();

    for (int tt = 0; tt < EP_TILES; ++tt) {
        const int cur = tt & 1;
        if (tt + 1 < EP_TILES) STAGE(tt + 1, cur ^ 1);

        f32x4 acc[4][3];
        #pragma unroll
        for (int rt = 0; rt < 4; ++rt)
            #pragma unroll
            for (int ct = 0; ct < 3; ++ct)
                acc[rt][ct] = (f32x4){0.f, 0.f, 0.f, 0.f};

        const char* xb = (const char*)&xbuf[cur][0];
        #pragma unroll
        for (int ks = 0; ks < 6; ++ks) {
            bf16x8 af[4];
            #pragma unroll
            for (int rt = 0; rt < 4; ++rt) {
                const int row = rt * 16 + (l & 15);
                const int p = (ks * 4 + (l >> 4)) ^ (l & 7);   // row&7 == l&7
                af[rt] = *reinterpret_cast<const bf16x8*>(xb + row * ROWB + p * 16);
            }
            #pragma unroll
            for (int rt = 0; rt < 4; ++rt)
                #pragma unroll
                for (int ct = 0; ct < 3; ++ct)
                    acc[rt][ct] = __builtin_amdgcn_mfma_f32_16x16x32_bf16(
                        af[rt], bfr[ct][ks], acc[rt][ct], 0, 0, 0);
        }

        // b values for this tile's 2 supernodes (read BEFORE the barrier;
        // g writes after it — g aliases b rows in C)
        const size_t s0 = (size_t)(blockIdx.x * EP_TILES + tt) * 2;
        float bval[2][3];
        #pragma unroll
        for (int sn = 0; sn < 2; ++sn)
            #pragma unroll
            for (int ct = 0; ct < 3; ++ct)
                bval[sn][ct] = bf2f(bC[(s0 + sn) * 384 + w * 48 + ct * 16 + (l & 15)]);

        __syncthreads();   // (a) all b reads done; (b) next stage drained (vmcnt0);
                           // (c) LDS reads of cur done -> tile tt+2 may restage cur

        #pragma unroll
        for (int sn = 0; sn < 2; ++sn)
            #pragma unroll
            for (int ct = 0; ct < 3; ++ct) {
                float part = 0.f;
                #pragma unroll
                for (int rr = 0; rr < 2; ++rr)
                    #pragma unroll
                    for (int j = 0; j < 4; ++j)
                        gelu_acc(acc[sn * 2 + rr][ct][j] + bval[sn][ct], part);
                part += __shfl_xor(part, 16);
                part += __shfl_xor(part, 32);
                if (l < 16)
                    g[(s0 + sn) * HD + w * 48 + ct * 16 + l] = part * 0.03125f;
            }
    }
}

// ---------------------------------------------------------------------------
// out = A[rows,192] @ W[192,192] + bias   (f32)
// ---------------------------------------------------------------------------
__global__ __launch_bounds__(256, 2)
void gemm192_kernel(const float* __restrict__ A,
                    const float* __restrict__ W,
                    const float* __restrict__ bias,
                    float* __restrict__ out)
{
    __shared__ float xsf[64][196];
    __shared__ float wchunk[32][HD];
    const int t    = threadIdx.x;
    const int row0 = blockIdx.x * 64;

    const float4* ap = reinterpret_cast<const float4*>(A + (size_t)row0 * HD);
    #pragma unroll
    for (int q = 0; q < 12; ++q) {
        const int f4 = t + q * 256;
        const int r = f4 / 48, c = f4 % 48;
        *reinterpret_cast<float4*>(&xsf[r][c * 4]) = ap[f4];
    }

    const int tr = t >> 4;
    const int tc = t & 15;
    float acc[4][12];
    #pragma unroll
    for (int i = 0; i < 4; ++i)
        #pragma unroll
        for (int j = 0; j < 12; ++j) acc[i][j] = 0.f;

    for (int kc = 0; kc < 6; ++kc) {
        __syncthreads();
        {
            const float4* wp = reinterpret_cast<const float4*>(W + kc * 32 * HD);
            float4* wsp = reinterpret_cast<float4*>(&wchunk[0][0]);
            #pragma unroll
            for (int q = 0; q < 6; ++q) wsp[t + q * 256] = wp[t + q * 256];
        }
        __syncthreads();
        #pragma unroll 4
        for (int k = 0; k < 32; ++k) {
            const int kg = kc * 32 + k;
            float xv[4];
            #pragma unroll
            for (int i = 0; i < 4; ++i) xv[i] = xsf[tr * 4 + i][kg];
            float wv[12];
            #pragma unroll
            for (int j4 = 0; j4 < 3; ++j4)
                *reinterpret_cast<float4*>(&wv[j4 * 4]) =
                    *reinterpret_cast<const float4*>(&wchunk[k][tc * 12 + j4 * 4]);
            #pragma unroll
            for (int i = 0; i < 4; ++i)
                #pragma unroll
                for (int j = 0; j < 12; ++j)
                    acc[i][j] = fmaf(xv[i], wv[j], acc[i][j]);
        }
    }

    float bb[12];
    #pragma unroll
    for (int j = 0; j < 12; ++j) bb[j] = bias[tc * 12 + j];

    #pragma unroll
    for (int i = 0; i < 4; ++i) {
        float* o = out + (size_t)(row0 + tr * 4 + i) * HD + tc * 12;
        #pragma unroll
        for (int j4 = 0; j4 < 3; ++j4) {
            float4 v;
            v.x = acc[i][j4 * 4 + 0] + bb[j4 * 4 + 0];
            v.y = acc[i][j4 * 4 + 1] + bb[j4 * 4 + 1];
            v.z = acc[i][j4 * 4 + 2] + bb[j4 * 4 + 2];
            v.w = acc[i][j4 * 4 + 3] + bb[j4 * 4 + 3];
            *reinterpret_cast<float4*>(o + j4 * 4) = v;
        }
    }
}

extern "C" void kernel_launch(void* const* d_in, const int* in_sizes, int n_in,
                              void* d_out, int out_size, void* d_ws, size_t ws_size,
                              hipStream_t stream)
{
    const float* feat = (const float*)d_in[0];
    const float* pos  = (const float*)d_in[1];
    const int*   sup  = (const int*)d_in[2];
    const int*   src  = (const int*)d_in[4];
    const float* Win  = (const float*)d_in[6];
    const float* bin  = (const float*)d_in[7];
    const float* W1   = (const float*)d_in[8];   // [384,192]
    const float* b1   = (const float*)d_in[9];
    const float* W2   = (const float*)d_in[10];  // [192,192]
    const float* b2   = (const float*)d_in[11];

    char* ws = (char*)d_ws;
    unsigned short* Wt   = (unsigned short*)ws;              //  73728 B
    unsigned short* Wb   = (unsigned short*)(ws + 73728);    //  73728 B
    float*          Wint = (float*)(ws + 147456);            //  12288 B
    unsigned short* x    = (unsigned short*)(ws + 159744);   // 100663296 B
    char*           C    = ws + 159744 + 100663296;          //  12582912 B
    float* out = (float*)d_out;

    prep_kernel<<<300, 256, 0, stream>>>(W1, Win, Wt, Wb, Wint);
    // x (bf16, chunk-swizzled), 1024 blocks x 256 rows
    xcomp_kernel<<<N_NODES / 256, 256, 0, stream>>>(feat, pos, Wint, bin, x);
    // b = x[sup] @ W1_bot + b1 -> bf16 rows in C (stride 384 elems)
    agemm_kernel<true><<<N_SUP / 64, 256, 0, stream>>>(
        x, sup, Wb, b1, (unsigned short*)C, 384, 1);
    // g = segment-mean(gelu(x[src]@W1_top + b)) -> f32 in place over C
    edgepool_kernel<<<N_SUP / (2 * EP_TILES), 256, 0, stream>>>(
        x, src, Wt, (const unsigned short*)C, (float*)C);
    // out = g @ W2 + b2
    gemm192_kernel<<<N_SUP / 64, 256, 0, stream>>>((const float*)C, W2, b2, out);
}